// Round 2
// baseline (1173.105 us; speedup 1.0000x reference)
//
#include <hip/hip_runtime.h>
#include <hip/hip_bf16.h>
#include <hip/hip_fp16.h>

// Shapes: L=S=1024, N=8, H=8, E=512, Dh=64, B=N*H=64, scaling=1/8.
// ALL inputs fp32 (per reference dtypes); d_out fp32:
//   [attn_output (L,N,E) | avg_w (N,L,S)] = 12,582,912 floats.
// Internal pipeline: fp16 MFMA (16x16x32), fp32 accumulate.

typedef float     f32x4  __attribute__((ext_vector_type(4)));
typedef _Float16  f16x8  __attribute__((ext_vector_type(8)));

#define MFMA_F16  __builtin_amdgcn_mfma_f32_16x16x32_f16

__device__ __forceinline__ f16x8 ld8f(const float* __restrict__ p){
  const f32x4 a = *(const f32x4*)p;
  const f32x4 b = *(const f32x4*)(p + 4);
  f16x8 h;
#pragma unroll
  for (int t = 0; t < 4; ++t) { h[t] = (_Float16)a[t]; h[t + 4] = (_Float16)b[t]; }
  return h;
}

// ---------------------------------------------------------------------------
// K1: C[m,i] = (sum_j X[m,j]*W[i,j] + bias[i]) * scale;  M=8192, N=512, K=512
// mode 0: out[m*512+i] fp16 (q,k layout [l][b*64+d] / [s][b*64+d])
// mode 1: v transposed  out[b*65536 + d*1024 + s] fp16 (PV B-operand)
// ---------------------------------------------------------------------------
__global__ __launch_bounds__(256) void proj_gemm(
    const float* __restrict__ X, const float* __restrict__ W,
    const float* __restrict__ bias, _Float16* __restrict__ out,
    float scale, int mode)
{
  const int tid = threadIdx.x, wave = tid >> 6, lane = tid & 63;
  const int lrow = lane & 15, quad = lane >> 4;
  const int m_base = blockIdx.x * 64 + (wave >> 1) * 32;
  const int n_base = blockIdx.y * 64 + (wave & 1) * 32;
  f32x4 acc[2][2] = {};
#pragma unroll 2
  for (int k0 = 0; k0 < 512; k0 += 32) {
    const int ko = k0 + quad * 8;
    f16x8 a0 = ld8f(X + (size_t)(m_base + lrow) * 512 + ko);
    f16x8 a1 = ld8f(X + (size_t)(m_base + 16 + lrow) * 512 + ko);
    f16x8 b0 = ld8f(W + (size_t)(n_base + lrow) * 512 + ko);
    f16x8 b1 = ld8f(W + (size_t)(n_base + 16 + lrow) * 512 + ko);
    acc[0][0] = MFMA_F16(a0, b0, acc[0][0], 0, 0, 0);
    acc[0][1] = MFMA_F16(a0, b1, acc[0][1], 0, 0, 0);
    acc[1][0] = MFMA_F16(a1, b0, acc[1][0], 0, 0, 0);
    acc[1][1] = MFMA_F16(a1, b1, acc[1][1], 0, 0, 0);
  }
#pragma unroll
  for (int i = 0; i < 2; ++i)
#pragma unroll
  for (int j = 0; j < 2; ++j) {
    const int ncol = n_base + j * 16 + lrow;
    const float bv = bias[ncol];
#pragma unroll
    for (int r = 0; r < 4; ++r) {
      const int m = m_base + i * 16 + quad * 4 + r;
      const float val = (acc[i][j][r] + bv) * scale;
      if (mode == 0) {
        out[(size_t)m * 512 + ncol] = (_Float16)val;
      } else {
        const int s = m >> 3, nn = m & 7, h = ncol >> 6, d = ncol & 63;
        out[(size_t)(nn * 8 + h) * 65536 + (size_t)d * 1024 + s] = (_Float16)val;
      }
    }
  }
}

// ---------------------------------------------------------------------------
// K8: out0[m,i] = sum_j ctx2[m,j]*Wo[i,j] + bo[i]   (fp32 out)
// ---------------------------------------------------------------------------
__global__ __launch_bounds__(256) void out_gemm(
    const _Float16* __restrict__ X, const float* __restrict__ W,
    const float* __restrict__ bias, float* __restrict__ out)
{
  const int tid = threadIdx.x, wave = tid >> 6, lane = tid & 63;
  const int lrow = lane & 15, quad = lane >> 4;
  const int m_base = blockIdx.x * 64 + (wave >> 1) * 32;
  const int n_base = blockIdx.y * 64 + (wave & 1) * 32;
  f32x4 acc[2][2] = {};
#pragma unroll 2
  for (int k0 = 0; k0 < 512; k0 += 32) {
    const int ko = k0 + quad * 8;
    f16x8 a0 = *(const f16x8*)(X + (size_t)(m_base + lrow) * 512 + ko);
    f16x8 a1 = *(const f16x8*)(X + (size_t)(m_base + 16 + lrow) * 512 + ko);
    f16x8 b0 = ld8f(W + (size_t)(n_base + lrow) * 512 + ko);
    f16x8 b1 = ld8f(W + (size_t)(n_base + 16 + lrow) * 512 + ko);
    acc[0][0] = MFMA_F16(a0, b0, acc[0][0], 0, 0, 0);
    acc[0][1] = MFMA_F16(a0, b1, acc[0][1], 0, 0, 0);
    acc[1][0] = MFMA_F16(a1, b0, acc[1][0], 0, 0, 0);
    acc[1][1] = MFMA_F16(a1, b1, acc[1][1], 0, 0, 0);
  }
#pragma unroll
  for (int i = 0; i < 2; ++i)
#pragma unroll
  for (int j = 0; j < 2; ++j) {
    const int ncol = n_base + j * 16 + lrow;
    const float bv = bias[ncol];
#pragma unroll
    for (int r = 0; r < 4; ++r) {
      const int m = m_base + i * 16 + quad * 4 + r;
      out[(size_t)m * 512 + ncol] = acc[i][j][r] + bv;
    }
  }
}

// ---------------------------------------------------------------------------
// K2: content scores per b: S_b[l,s] = sum_d q[l,b,d]*k[s,b,d]  -> sbuf fp16
// ---------------------------------------------------------------------------
__global__ __launch_bounds__(256) void qk_content(
    const _Float16* __restrict__ qb, const _Float16* __restrict__ kb,
    _Float16* __restrict__ sbuf)
{
  const int b = blockIdx.z;
  const int tid = threadIdx.x, wave = tid >> 6, lane = tid & 63;
  const int lrow = lane & 15, quad = lane >> 4;
  const int l_base = blockIdx.x * 64 + (wave >> 1) * 32;
  const int s_base = blockIdx.y * 64 + (wave & 1) * 32;
  const _Float16* qp = qb + b * 64;
  const _Float16* kp = kb + b * 64;
  f32x4 acc[2][2] = {};
#pragma unroll
  for (int k0 = 0; k0 < 64; k0 += 32) {
    const int ko = k0 + quad * 8;
    f16x8 a0 = *(const f16x8*)(qp + (size_t)(l_base + lrow) * 4096 + ko);
    f16x8 a1 = *(const f16x8*)(qp + (size_t)(l_base + 16 + lrow) * 4096 + ko);
    f16x8 b0 = *(const f16x8*)(kp + (size_t)(s_base + lrow) * 4096 + ko);
    f16x8 b1 = *(const f16x8*)(kp + (size_t)(s_base + 16 + lrow) * 4096 + ko);
    acc[0][0] = MFMA_F16(a0, b0, acc[0][0], 0, 0, 0);
    acc[0][1] = MFMA_F16(a0, b1, acc[0][1], 0, 0, 0);
    acc[1][0] = MFMA_F16(a1, b0, acc[1][0], 0, 0, 0);
    acc[1][1] = MFMA_F16(a1, b1, acc[1][1], 0, 0, 0);
  }
  _Float16* sp = sbuf + (size_t)b * 1048576;
#pragma unroll
  for (int i = 0; i < 2; ++i)
#pragma unroll
  for (int j = 0; j < 2; ++j)
#pragma unroll
  for (int r = 0; r < 4; ++r)
    sp[(size_t)(l_base + i * 16 + quad * 4 + r) * 1024 + s_base + j * 16 + lrow] =
        (_Float16)acc[i][j][r];
}

// ---------------------------------------------------------------------------
// K3: pos scores per l: sbuf[b,l,s] += sum_d q[l,b,d]*pos_k[l,s,d]
// ---------------------------------------------------------------------------
__global__ __launch_bounds__(256) void qk_pos(
    const _Float16* __restrict__ qb, const float* __restrict__ pk,
    _Float16* __restrict__ sbuf)
{
  const int l = blockIdx.x;
  const int tid = threadIdx.x, wave = tid >> 6, lane = tid & 63;
  const int lrow = lane & 15, quad = lane >> 4;
  const int b_base = (wave >> 1) * 32;
  const int s_base = blockIdx.y * 64 + (wave & 1) * 32;
  const _Float16* qp = qb + (size_t)l * 4096;
  const float* pp = pk + (size_t)l * 65536;
  f32x4 acc[2][2] = {};
#pragma unroll
  for (int k0 = 0; k0 < 64; k0 += 32) {
    const int ko = k0 + quad * 8;
    f16x8 a0 = *(const f16x8*)(qp + (size_t)(b_base + lrow) * 64 + ko);
    f16x8 a1 = *(const f16x8*)(qp + (size_t)(b_base + 16 + lrow) * 64 + ko);
    f16x8 b0 = ld8f(pp + (size_t)(s_base + lrow) * 64 + ko);
    f16x8 b1 = ld8f(pp + (size_t)(s_base + 16 + lrow) * 64 + ko);
    acc[0][0] = MFMA_F16(a0, b0, acc[0][0], 0, 0, 0);
    acc[0][1] = MFMA_F16(a0, b1, acc[0][1], 0, 0, 0);
    acc[1][0] = MFMA_F16(a1, b0, acc[1][0], 0, 0, 0);
    acc[1][1] = MFMA_F16(a1, b1, acc[1][1], 0, 0, 0);
  }
#pragma unroll
  for (int i = 0; i < 2; ++i)
#pragma unroll
  for (int j = 0; j < 2; ++j)
#pragma unroll
  for (int r = 0; r < 4; ++r) {
    const size_t idx = (size_t)(b_base + i * 16 + quad * 4 + r) * 1048576 +
                       (size_t)l * 1024 + s_base + j * 16 + lrow;
    sbuf[idx] = (_Float16)((float)sbuf[idx] + acc[i][j][r]);
  }
}

// ---------------------------------------------------------------------------
// K4: per (n,l): softmax over s for all 8 heads (one wave each), write w fp16
//     back in place; avg over heads -> fp32 avg_w output.
// ---------------------------------------------------------------------------
__global__ __launch_bounds__(512) void softmax_avg(
    _Float16* __restrict__ sbuf, float* __restrict__ avg_out)
{
  __shared__ _Float16 lds[8 * 1088];
  const int bx = blockIdx.x;
  const int n = bx >> 10, l = bx & 1023;
  const int tid = threadIdx.x, h = tid >> 6, lane = tid & 63;
  _Float16* row = sbuf + (size_t)(n * 8 + h) * 1048576 + (size_t)l * 1024;
  float x[16];
#pragma unroll
  for (int i = 0; i < 16; ++i) x[i] = (float)row[lane + 64 * i];
  float m = x[0];
#pragma unroll
  for (int i = 1; i < 16; ++i) m = fmaxf(m, x[i]);
#pragma unroll
  for (int off = 32; off > 0; off >>= 1) m = fmaxf(m, __shfl_xor(m, off));
  float z = 0.f;
#pragma unroll
  for (int i = 0; i < 16; ++i) { x[i] = __expf(x[i] - m); z += x[i]; }
#pragma unroll
  for (int off = 32; off > 0; off >>= 1) z += __shfl_xor(z, off);
  const float inv = 1.0f / z;
#pragma unroll
  for (int i = 0; i < 16; ++i) {
    const _Float16 w = (_Float16)(x[i] * inv);
    row[lane + 64 * i] = w;
    lds[h * 1088 + lane + 64 * i] = w;
  }
  __syncthreads();
  float* ao = avg_out + (size_t)n * 1048576 + (size_t)l * 1024;
  for (int s = tid; s < 1024; s += 512) {
    float acc = 0.f;
#pragma unroll
    for (int h2 = 0; h2 < 8; ++h2) acc += (float)lds[h2 * 1088 + s];
    ao[s] = acc * 0.125f;
  }
}

// ---------------------------------------------------------------------------
// K6: content PV per b: ctx[l, b*64+d] = sum_s w[b,l,s]*v[b,s,d]  (fp32)
// ---------------------------------------------------------------------------
__global__ __launch_bounds__(256) void pv_content(
    const _Float16* __restrict__ sbuf, const _Float16* __restrict__ vT,
    float* __restrict__ ctx)
{
  const int b = blockIdx.x;
  const int tid = threadIdx.x, wave = tid >> 6, lane = tid & 63;
  const int lrow = lane & 15, quad = lane >> 4;
  const int l_base = blockIdx.y * 64 + (wave >> 1) * 32;
  const int d_base = (wave & 1) * 32;
  const _Float16* wp = sbuf + (size_t)b * 1048576;
  const _Float16* vp = vT + (size_t)b * 65536;
  f32x4 acc[2][2] = {};
  for (int s0 = 0; s0 < 1024; s0 += 32) {
    const int so = s0 + quad * 8;
    f16x8 a0 = *(const f16x8*)(wp + (size_t)(l_base + lrow) * 1024 + so);
    f16x8 a1 = *(const f16x8*)(wp + (size_t)(l_base + 16 + lrow) * 1024 + so);
    f16x8 b0 = *(const f16x8*)(vp + (size_t)(d_base + lrow) * 1024 + so);
    f16x8 b1 = *(const f16x8*)(vp + (size_t)(d_base + 16 + lrow) * 1024 + so);
    acc[0][0] = MFMA_F16(a0, b0, acc[0][0], 0, 0, 0);
    acc[0][1] = MFMA_F16(a0, b1, acc[0][1], 0, 0, 0);
    acc[1][0] = MFMA_F16(a1, b0, acc[1][0], 0, 0, 0);
    acc[1][1] = MFMA_F16(a1, b1, acc[1][1], 0, 0, 0);
  }
#pragma unroll
  for (int i = 0; i < 2; ++i)
#pragma unroll
  for (int j = 0; j < 2; ++j)
#pragma unroll
  for (int r = 0; r < 4; ++r)
    ctx[(size_t)(l_base + i * 16 + quad * 4 + r) * 4096 + b * 64 + d_base + j * 16 + lrow] =
        acc[i][j][r];
}

// ---------------------------------------------------------------------------
// K7: pos PV per l: ctx2[l, b*64+d] = fp16(ctx + sum_s w[b,l,s]*pos_v[l,s,d])
// ---------------------------------------------------------------------------
__global__ __launch_bounds__(256) void pv_pos(
    const _Float16* __restrict__ sbuf, const float* __restrict__ pv,
    const float* __restrict__ ctx, _Float16* __restrict__ ctx2)
{
  const int l = blockIdx.x;
  const int tid = threadIdx.x, wave = tid >> 6, lane = tid & 63;
  const int lrow = lane & 15, quad = lane >> 4;
  const int b_base = (wave >> 1) * 32;
  const int d_base = (wave & 1) * 32;
  const float* pp = pv + (size_t)l * 65536;
  f32x4 acc[2][2] = {};
  for (int s0 = 0; s0 < 1024; s0 += 32) {
    const int so = s0 + quad * 8;
    f16x8 a0 = *(const f16x8*)(sbuf + (size_t)(b_base + lrow) * 1048576 + (size_t)l * 1024 + so);
    f16x8 a1 = *(const f16x8*)(sbuf + (size_t)(b_base + 16 + lrow) * 1048576 + (size_t)l * 1024 + so);
    f16x8 b0, b1;
#pragma unroll
    for (int t = 0; t < 8; ++t) {
      b0[t] = (_Float16)pp[(size_t)(so + t) * 64 + d_base + lrow];
      b1[t] = (_Float16)pp[(size_t)(so + t) * 64 + d_base + 16 + lrow];
    }
    acc[0][0] = MFMA_F16(a0, b0, acc[0][0], 0, 0, 0);
    acc[0][1] = MFMA_F16(a0, b1, acc[0][1], 0, 0, 0);
    acc[1][0] = MFMA_F16(a1, b0, acc[1][0], 0, 0, 0);
    acc[1][1] = MFMA_F16(a1, b1, acc[1][1], 0, 0, 0);
  }
#pragma unroll
  for (int i = 0; i < 2; ++i)
#pragma unroll
  for (int j = 0; j < 2; ++j)
#pragma unroll
  for (int r = 0; r < 4; ++r) {
    const size_t idx = (size_t)l * 4096 + (size_t)(b_base + i * 16 + quad * 4 + r) * 64 +
                       d_base + j * 16 + lrow;
    ctx2[idx] = (_Float16)(ctx[idx] + acc[i][j][r]);
  }
}

// ---------------------------------------------------------------------------
extern "C" void kernel_launch(void* const* d_in, const int* in_sizes, int n_in,
                              void* d_out, int out_size, void* d_ws, size_t ws_size,
                              hipStream_t stream)
{
  const float* query = (const float*)d_in[0];
  const float* key   = (const float*)d_in[1];
  const float* value = (const float*)d_in[2];
  const float* pos_k = (const float*)d_in[3];
  const float* pos_v = (const float*)d_in[4];
  const float* Wq = (const float*)d_in[5];
  const float* bq = (const float*)d_in[6];
  const float* Wk = (const float*)d_in[7];
  const float* bk = (const float*)d_in[8];
  const float* Wv = (const float*)d_in[9];
  const float* bv = (const float*)d_in[10];
  const float* Wo = (const float*)d_in[11];
  const float* bo = (const float*)d_in[12];

  char* ws = (char*)d_ws;
  _Float16* qb   = (_Float16*)(ws);                        // 8 MiB  [l][b*64+d]
  _Float16* kb   = (_Float16*)(ws + (size_t)(8u  << 20));  // 8 MiB  [s][b*64+d]
  _Float16* vT   = (_Float16*)(ws + (size_t)(16u << 20));  // 8 MiB  [b][d][s]
  _Float16* sbuf = (_Float16*)(ws + (size_t)(24u << 20));  // 128 MiB [b][l][s]
  float*    ctx  = (float*)   (ws + (size_t)(152u << 20)); // 16 MiB [l][b*64+d]
  _Float16* ctx2 = (_Float16*)(ws + (size_t)(168u << 20)); // 8 MiB  [l][b*64+d]

  float* out0 = (float*)d_out;
  float* avg  = out0 + (size_t)4194304;

  dim3 blk(256);
  proj_gemm<<<dim3(128, 8), blk, 0, stream>>>(query, Wq, bq, qb, 0.125f, 0);
  proj_gemm<<<dim3(128, 8), blk, 0, stream>>>(key,   Wk, bk, kb, 1.0f, 0);
  proj_gemm<<<dim3(128, 8), blk, 0, stream>>>(value, Wv, bv, vT, 1.0f, 1);
  qk_content<<<dim3(16, 16, 64), blk, 0, stream>>>(qb, kb, sbuf);
  qk_pos<<<dim3(1024, 16), blk, 0, stream>>>(qb, pos_k, sbuf);
  softmax_avg<<<dim3(8192), dim3(512), 0, stream>>>(sbuf, avg);
  pv_content<<<dim3(64, 16), blk, 0, stream>>>(sbuf, vT, ctx);
  pv_pos<<<dim3(1024), blk, 0, stream>>>(sbuf, pos_v, ctx, ctx2);
  out_gemm<<<dim3(128, 8), blk, 0, stream>>>(ctx2, Wo, bo, out0);
}